// Round 1
// 580.364 us; speedup vs baseline: 1.0053x; 1.0053x over previous
//
#include <hip/hip_runtime.h>

// PGWCrossAttention on MI355X (gfx950), bf16 MFMA pipeline.
// R6: kill the latency-bound k_logits (168us @ 8% MfmaUtil / 17% HBM / 32% VALU —
// all pipes idle => serialization). Split along the dsum dependency instead of
// recomputing the elec GEMM twice:
//   k_sd      = pass1 + struct GEMM, writes packed (bf16 s/16 | bf16 d) once.
//   k_softmax = pure streaming exp: coalesced pi/sd reads, direct rowsum store
//               (no atomics, no scattered 4B loads, near-HBM-roofline).
// sd buffer (4B/elem) processed 2 batches/chunk = exactly 32MiB, placed in the
// ctx+hbuf slots (dead until k_fused). 4 chunk pairs.
#define Bsz 8
#define Nq  2048
#define Mk  2048
#define BKt 32          // K-tile per MFMA step

typedef __attribute__((ext_vector_type(8))) short   short8;   // 8 bf16 (4 VGPRs)
typedef __attribute__((ext_vector_type(4))) float   floatx4;  // MFMA acc

__device__ __forceinline__ unsigned short f2bf(float f) {
  union { float f; unsigned u; } x; x.f = f;
  unsigned r = x.u + 0x7fffu + ((x.u >> 16) & 1u);   // RNE
  return (unsigned short)(r >> 16);
}
__device__ __forceinline__ float bf2f(unsigned short s) {
  union { unsigned u; float f; } x; x.u = ((unsigned)s) << 16;
  return x.f;
}

// ---------------------------------------------------------------------------
// NT GEMM core 128x128: C += A[128,K] . B[128,K]^T, fp32 acc, 2x2 waves,
// 4x4 16x16 frags/wave. Frag layout (m89/m91): A/B elem[m=lane&15][k=(lane>>4)*8+j];
// C/D: col=lane&15, row=(lane>>4)*4+reg. VGPR staging (async16 regressed, R2).
// ---------------------------------------------------------------------------
__device__ __forceinline__ void gemm_core_nt(
    const unsigned short* __restrict__ A, int lda,
    const unsigned short* __restrict__ B, int ldb,
    int K, unsigned short* ldsA, unsigned short* ldsB,
    floatx4 (&acc)[4][4])
{
  const int tid  = threadIdx.x;
  const int lane = tid & 63;
  const int sr   = tid >> 2;          // staging row 0..63
  const int sc   = (tid & 3) << 3;    // staging col 0/8/16/24
  const int wid  = tid >> 6;
  const int wm   = wid & 1;
  const int wn   = wid >> 1;
  const int fr   = lane & 15;
  const int fk   = (lane >> 4) << 3;

  const unsigned short* a0p = A + (size_t)sr * lda + sc;
  const unsigned short* a1p = A + (size_t)(sr + 64) * lda + sc;
  const unsigned short* b0p = B + (size_t)sr * ldb + sc;
  const unsigned short* b1p = B + (size_t)(sr + 64) * ldb + sc;
  uint4* sa0 = (uint4*)(ldsA + sr * BKt + sc);
  uint4* sa1 = (uint4*)(ldsA + (sr + 64) * BKt + sc);
  uint4* sb0 = (uint4*)(ldsB + sr * BKt + sc);
  uint4* sb1 = (uint4*)(ldsB + (sr + 64) * BKt + sc);
  const unsigned short* fa = ldsA + (wm * 64 + fr) * BKt + fk;
  const unsigned short* fb = ldsB + (wn * 64 + fr) * BKt + fk;

  for (int k0 = 0; k0 < K; k0 += BKt) {
    uint4 a0 = *(const uint4*)a0p; a0p += BKt;
    uint4 a1 = *(const uint4*)a1p; a1p += BKt;
    uint4 b0 = *(const uint4*)b0p; b0p += BKt;
    uint4 b1 = *(const uint4*)b1p; b1p += BKt;
    __syncthreads();                  // protect prior iter's frag reads
    *sa0 = a0; *sa1 = a1; *sb0 = b0; *sb1 = b1;
    __syncthreads();
    short8 af[4], bfr[4];
#pragma unroll
    for (int i = 0; i < 4; i++) af[i]  = *(const short8*)(fa + i * 16 * BKt);
#pragma unroll
    for (int i = 0; i < 4; i++) bfr[i] = *(const short8*)(fb + i * 16 * BKt);
#pragma unroll
    for (int i = 0; i < 4; i++)
#pragma unroll
      for (int j = 0; j < 4; j++)
        acc[i][j] = __builtin_amdgcn_mfma_f32_16x16x32_bf16(af[i], bfr[j], acc[i][j], 0, 0, 0);
  }
}

// ---------------------------------------------------------------------------
// NT GEMM core 128x64: C += A[128,K] . B[64,K]^T. 2x2 waves, wave tile 64x32,
// acc[4][2] = 32 AGPR.
// ---------------------------------------------------------------------------
__device__ __forceinline__ void gemm_core_nt64(
    const unsigned short* __restrict__ A, int lda,
    const unsigned short* __restrict__ B, int ldb,
    int K, unsigned short* ldsA, unsigned short* ldsB,
    floatx4 (&acc)[4][2])
{
  const int tid  = threadIdx.x;
  const int lane = tid & 63;
  const int sr   = tid >> 2;
  const int sc   = (tid & 3) << 3;
  const int wid  = tid >> 6;
  const int wm   = wid & 1;
  const int wn   = wid >> 1;
  const int fr   = lane & 15;
  const int fk   = (lane >> 4) << 3;

  const unsigned short* a0p = A + (size_t)sr * lda + sc;
  const unsigned short* a1p = A + (size_t)(sr + 64) * lda + sc;
  const unsigned short* bp  = B + (size_t)sr * ldb + sc;
  uint4* sa0 = (uint4*)(ldsA + sr * BKt + sc);
  uint4* sa1 = (uint4*)(ldsA + (sr + 64) * BKt + sc);
  uint4* sb  = (uint4*)(ldsB + sr * BKt + sc);
  const unsigned short* fa = ldsA + (wm * 64 + fr) * BKt + fk;
  const unsigned short* fb = ldsB + (wn * 32 + fr) * BKt + fk;

  for (int k0 = 0; k0 < K; k0 += BKt) {
    uint4 a0 = *(const uint4*)a0p; a0p += BKt;
    uint4 a1 = *(const uint4*)a1p; a1p += BKt;
    uint4 b0 = *(const uint4*)bp;  bp  += BKt;
    __syncthreads();
    *sa0 = a0; *sa1 = a1; *sb = b0;
    __syncthreads();
    short8 af[4], bfr[2];
#pragma unroll
    for (int i = 0; i < 4; i++) af[i]  = *(const short8*)(fa + i * 16 * BKt);
#pragma unroll
    for (int j = 0; j < 2; j++) bfr[j] = *(const short8*)(fb + j * 16 * BKt);
#pragma unroll
    for (int i = 0; i < 4; i++)
#pragma unroll
      for (int j = 0; j < 2; j++)
        acc[i][j] = __builtin_amdgcn_mfma_f32_16x16x32_bf16(af[i], bfr[j], acc[i][j], 0, 0, 0);
  }
}

#define EPILOGUE_VARS \
  const int lane = threadIdx.x & 63; \
  const int wid  = threadIdx.x >> 6; \
  const int wm   = wid & 1; \
  const int wn   = wid >> 1; \
  const int r4   = (lane >> 4) * 4;  \
  const int cn   = lane & 15; \
  (void)wid;

// ---------------------------------------------------------------------------
// Projection GEMM, A in fp32 (bf16-cast during staging). 128x128 tile.
// ---------------------------------------------------------------------------
__global__ __launch_bounds__(256, 2) void k_proj(
    const float* __restrict__ A, const unsigned short* __restrict__ Bw,
    const float* __restrict__ bias, unsigned short* __restrict__ Cout,
    int Ncols, int K)
{
  __shared__ alignas(16) unsigned short ldsA[128 * BKt];
  __shared__ alignas(16) unsigned short ldsB[128 * BKt];
  floatx4 acc[4][4];
#pragma unroll
  for (int i = 0; i < 4; i++)
#pragma unroll
    for (int j = 0; j < 4; j++)
#pragma unroll
      for (int t = 0; t < 4; t++) acc[i][j][t] = 0.f;

  const int tid = threadIdx.x;
  const int ar  = tid >> 1;            // A staging row 0..127
  const int ac  = (tid & 1) << 4;      // A staging col 0/16
  const int sr  = tid >> 2;            // B staging row 0..63
  const int sc  = (tid & 3) << 3;

  const float* ap = A + ((size_t)blockIdx.x * 128 + ar) * K + ac;
  const unsigned short* b0p = Bw + ((size_t)blockIdx.y * 128 + sr) * K + sc;
  const unsigned short* b1p = b0p + (size_t)64 * K;
  uint4* sa  = (uint4*)(ldsA + ar * BKt + ac);
  uint4* sb0 = (uint4*)(ldsB + sr * BKt + sc);
  uint4* sb1 = (uint4*)(ldsB + (sr + 64) * BKt + sc);

  {
    const int lane = tid & 63;
    const int wm   = (tid >> 6) & 1;
    const int wn   = tid >> 7;
    const int fr   = lane & 15;
    const int fk   = (lane >> 4) << 3;
    const unsigned short* fa = ldsA + (wm * 64 + fr) * BKt + fk;
    const unsigned short* fb = ldsB + (wn * 64 + fr) * BKt + fk;

    for (int k0 = 0; k0 < K; k0 += BKt) {
      float4 f0 = *(const float4*)(ap + 0);
      float4 f1 = *(const float4*)(ap + 4);
      float4 f2 = *(const float4*)(ap + 8);
      float4 f3 = *(const float4*)(ap + 12);
      ap += BKt;
      uint4 b0 = *(const uint4*)b0p; b0p += BKt;
      uint4 b1 = *(const uint4*)b1p; b1p += BKt;
      uint4 pa, pb;
      pa.x = f2bf(f0.x) | ((unsigned)f2bf(f0.y) << 16);
      pa.y = f2bf(f0.z) | ((unsigned)f2bf(f0.w) << 16);
      pa.z = f2bf(f1.x) | ((unsigned)f2bf(f1.y) << 16);
      pa.w = f2bf(f1.z) | ((unsigned)f2bf(f1.w) << 16);
      pb.x = f2bf(f2.x) | ((unsigned)f2bf(f2.y) << 16);
      pb.y = f2bf(f2.z) | ((unsigned)f2bf(f2.w) << 16);
      pb.z = f2bf(f3.x) | ((unsigned)f2bf(f3.y) << 16);
      pb.w = f2bf(f3.z) | ((unsigned)f2bf(f3.w) << 16);
      __syncthreads();
      sa[0] = pa; sa[1] = pb;
      *sb0 = b0; *sb1 = b1;
      __syncthreads();
      short8 af[4], bfr[4];
#pragma unroll
      for (int i = 0; i < 4; i++) af[i]  = *(const short8*)(fa + i * 16 * BKt);
#pragma unroll
      for (int i = 0; i < 4; i++) bfr[i] = *(const short8*)(fb + i * 16 * BKt);
#pragma unroll
      for (int i = 0; i < 4; i++)
#pragma unroll
        for (int j = 0; j < 4; j++)
          acc[i][j] = __builtin_amdgcn_mfma_f32_16x16x32_bf16(af[i], bfr[j], acc[i][j], 0, 0, 0);
    }
  }

  EPILOGUE_VARS
#pragma unroll
  for (int i = 0; i < 4; i++) {
#pragma unroll
    for (int j = 0; j < 4; j++) {
      int gc = blockIdx.y * 128 + wn * 64 + j * 16 + cn;
      float bv = bias[gc];
#pragma unroll
      for (int r = 0; r < 4; r++) {
        int gr = blockIdx.x * 128 + wm * 64 + i * 16 + r4 + r;
        Cout[(size_t)gr * Ncols + gc] = f2bf(acc[i][j][r] + bv);
      }
    }
  }
}

// ---------------------------------------------------------------------------
// MLP GEMM (bf16 A). MODE 1: silu -> bf16. MODE 2: store fp32.
// ---------------------------------------------------------------------------
template<int MODE>
__global__ __launch_bounds__(256, 3) void k_gemm_bias(
    const unsigned short* __restrict__ A, const unsigned short* __restrict__ Bw,
    const float* __restrict__ bias, void* __restrict__ Cout, int Ncols, int K)
{
  __shared__ alignas(16) unsigned short ldsA[128 * BKt];
  __shared__ alignas(16) unsigned short ldsB[128 * BKt];
  floatx4 acc[4][4];
#pragma unroll
  for (int i = 0; i < 4; i++)
#pragma unroll
    for (int j = 0; j < 4; j++)
#pragma unroll
      for (int t = 0; t < 4; t++) acc[i][j][t] = 0.f;

  const unsigned short* Ab = A + (size_t)blockIdx.x * 128 * K;
  const unsigned short* Bb = Bw + (size_t)blockIdx.y * 128 * K;
  gemm_core_nt(Ab, K, Bb, K, K, ldsA, ldsB, acc);

  EPILOGUE_VARS
#pragma unroll
  for (int i = 0; i < 4; i++) {
#pragma unroll
    for (int j = 0; j < 4; j++) {
      int gc = blockIdx.y * 128 + wn * 64 + j * 16 + cn;
      float bv = bias[gc];
#pragma unroll
      for (int r = 0; r < 4; r++) {
        int gr = blockIdx.x * 128 + wm * 64 + i * 16 + r4 + r;
        float v = acc[i][j][r] + bv;
        if constexpr (MODE == 1) v = v / (1.f + __expf(-v));
        if constexpr (MODE == 2)
          ((float*)Cout)[(size_t)gr * Ncols + gc] = v;
        else
          ((unsigned short*)Cout)[(size_t)gr * Ncols + gc] = f2bf(v);
      }
    }
  }
}

// ---------------------------------------------------------------------------
// k_sd: struct + elec GEMMs at 128x128 tiles (each computed ONCE).
// Writes packed uint32 per element: lo = bf16(s * 0.0625), hi = bf16(d),
// accumulates dsum[b] (sum of d). sd buffer is chunk-local (2 batches).
// ---------------------------------------------------------------------------
__global__ __launch_bounds__(256, 2) void k_sd(
    const unsigned short* __restrict__ Xq, const unsigned short* __restrict__ Xk,
    const float* __restrict__ q2, const float* __restrict__ k2,
    int b0, float* __restrict__ dsum, unsigned* __restrict__ sd)
{
  __shared__ alignas(16) unsigned short ldsA[128 * BKt];
  __shared__ alignas(16) unsigned short ldsB[128 * BKt];
  floatx4 accS[4][4], accE[4][4];
#pragma unroll
  for (int i = 0; i < 4; i++)
#pragma unroll
    for (int j = 0; j < 4; j++)
#pragma unroll
      for (int t = 0; t < 4; t++) { accS[i][j][t] = 0.f; accE[i][j][t] = 0.f; }

  const int z = blockIdx.z;           // chunk-local batch 0/1
  const int b = b0 + z;
  const unsigned short* Aq = Xq + ((size_t)(b * Nq) + blockIdx.x * 128) * 512;
  const unsigned short* Bk = Xk + ((size_t)(b * Mk) + blockIdx.y * 128) * 1024;
  gemm_core_nt(Aq,       512, Bk,       1024, 256, ldsA, ldsB, accS);  // struct
  gemm_core_nt(Aq + 256, 512, Bk + 512, 1024, 256, ldsA, ldsB, accE);  // elec

  EPILOGUE_VARS
  float kkv[4];
#pragma unroll
  for (int j = 0; j < 4; j++)
    kkv[j] = k2[b * Mk + blockIdx.y * 128 + wn * 64 + j * 16 + cn];

  float lsum = 0.f;
#pragma unroll
  for (int i = 0; i < 4; i++) {
#pragma unroll
    for (int r = 0; r < 4; r++) {
      const int n = blockIdx.x * 128 + wm * 64 + i * 16 + r4 + r;
      const float qq = q2[b * Nq + n];
      unsigned* srow = sd + (size_t)(z * Nq + n) * Mk;
#pragma unroll
      for (int j = 0; j < 4; j++) {
        const int m = blockIdx.y * 128 + wn * 64 + j * 16 + cn;
        float d = sqrtf(fmaxf(qq + kkv[j] - 2.f * accE[i][j][r], 1e-12f));
        lsum += d;
        srow[m] = (unsigned)f2bf(accS[i][j][r] * 0.0625f)
                | ((unsigned)f2bf(d) << 16);
      }
    }
  }
#pragma unroll
  for (int o = 32; o; o >>= 1) lsum += __shfl_down(lsum, o);
  __syncthreads();                    // ldsA frag reads done before reuse
  float* red = (float*)ldsA;
  if (lane == 0) red[wid] = lsum;
  __syncthreads();
  if (threadIdx.x == 0) atomicAdd(dsum + b, red[0] + red[1] + red[2] + red[3]);
}

// ---------------------------------------------------------------------------
// k_softmax: streaming. One wave per row: e = exp(s - ew*d/scale) * pi^gamma,
// attn (bf16 unnorm) + rowsum[row] (direct store, no atomics). Fully coalesced:
// uint4 sd loads, float4 pi loads, uint2 attn stores.
// ---------------------------------------------------------------------------
__global__ __launch_bounds__(256) void k_softmax(
    const unsigned* __restrict__ sd, const float* __restrict__ pi,
    const float* __restrict__ dsum, const float* __restrict__ gamma_p,
    const float* __restrict__ ew_p, int b0,
    unsigned short* __restrict__ attn, float* __restrict__ rowsum)
{
  const int wid  = threadIdx.x >> 6;
  const int lane = threadIdx.x & 63;
  const int rl   = blockIdx.x * 4 + wid;     // chunk-local row 0..4095
  const int b    = b0 + (rl >> 11);
  const int n    = rl & 2047;

  const float scale = fmaxf(dsum[b] * (1.f / (2048.f * 2048.f)), 1e-4f);
  const float einv  = ew_p[0] / scale;
  const float gv    = gamma_p[0];
  const bool  g1    = (gv == 1.0f);          // wave-uniform fast path

  const unsigned*  sp = sd  + (size_t)rl * Mk;
  const float*     pp = pi  + ((size_t)b * Nq + n) * Mk;
  unsigned short*  ap = attn + ((size_t)b * Nq + n) * Mk;

  float rs = 0.f;
  for (int it = 0; it < 8; ++it) {
    const int c = it * 256 + lane * 4;
    const uint4  sv = *(const uint4*)(sp + c);
    const float4 pv = *(const float4*)(pp + c);
    const unsigned uu[4]  = {sv.x, sv.y, sv.z, sv.w};
    const float    pp4[4] = {pv.x, pv.y, pv.z, pv.w};
    float e[4];
#pragma unroll
    for (int t = 0; t < 4; ++t) {
      union { unsigned u; float f; } cs, cd;
      cs.u = uu[t] << 16;                    // s * 0.0625
      cd.u = uu[t] & 0xffff0000u;            // d
      float p  = fmaxf(pp4[t], 1e-9f);
      float pf = g1 ? p : __expf(gv * __logf(p));
      e[t] = __expf(cs.f - einv * cd.f) * pf;
      rs += e[t];
    }
    uint2 st;
    st.x = (unsigned)f2bf(e[0]) | ((unsigned)f2bf(e[1]) << 16);
    st.y = (unsigned)f2bf(e[2]) | ((unsigned)f2bf(e[3]) << 16);
    *(uint2*)(ap + c) = st;
  }
#pragma unroll
  for (int o = 32; o; o >>= 1) rs += __shfl_down(rs, o);
  if (lane == 0) rowsum[b * Nq + n] = rs;
}

// ---------------------------------------------------------------------------
// PV: ctx[b,n,gc] = (attn_unnorm @ [Vs|Ve]) / rowsum[n]. 128x64 tile.
// ---------------------------------------------------------------------------
__global__ __launch_bounds__(256, 3) void k_pv(
    const unsigned short* __restrict__ At, const unsigned short* __restrict__ VT,
    const float* __restrict__ rowsum, unsigned short* __restrict__ ctx)
{
  __shared__ alignas(16) unsigned short ldsA[128 * BKt];
  __shared__ alignas(16) unsigned short ldsB[64 * BKt];
  floatx4 acc[4][2];
#pragma unroll
  for (int i = 0; i < 4; i++)
#pragma unroll
    for (int j = 0; j < 2; j++)
#pragma unroll
      for (int t = 0; t < 4; t++) acc[i][j][t] = 0.f;

  const int b = blockIdx.z;
  const unsigned short* Ab = At + ((size_t)b * Nq + blockIdx.x * 128) * (size_t)Mk;
  const unsigned short* Bb = VT + ((size_t)b * 512 + blockIdx.y * 64) * (size_t)Mk;
  gemm_core_nt64(Ab, Mk, Bb, Mk, Mk, ldsA, ldsB, acc);

  EPILOGUE_VARS
  const int rowbase = b * Nq + blockIdx.x * 128 + wm * 64;
#pragma unroll
  for (int i = 0; i < 4; i++) {
    float rinv[4];
#pragma unroll
    for (int r = 0; r < 4; r++)
      rinv[r] = 1.f / rowsum[rowbase + i * 16 + r4 + r];
#pragma unroll
    for (int j = 0; j < 2; j++) {
      int gc = blockIdx.y * 64 + wn * 32 + j * 16 + cn;
#pragma unroll
      for (int r = 0; r < 4; r++) {
        int gr = blockIdx.x * 128 + wm * 64 + i * 16 + r4 + r;
        ctx[((size_t)b * Nq + gr) * 512 + gc] = f2bf(acc[i][j][r] * rinv[r]);
      }
    }
  }
}

// ---------------------------------------------------------------------------
// Small utility kernels
// ---------------------------------------------------------------------------
// transpose + concat weights -> bf16; concat biases; zero dsum
__global__ void k_prep_w(
    const float* __restrict__ Wqs, const float* __restrict__ Wqe,
    const float* __restrict__ Wks, const float* __restrict__ Wvs,
    const float* __restrict__ Wke, const float* __restrict__ Wve,
    const float* __restrict__ W1,  const float* __restrict__ W2,
    const float* __restrict__ bqs, const float* __restrict__ bqe,
    const float* __restrict__ bks, const float* __restrict__ bvs,
    const float* __restrict__ bke, const float* __restrict__ bve,
    unsigned short* __restrict__ WqT, unsigned short* __restrict__ WkT,
    unsigned short* __restrict__ W1T, unsigned short* __restrict__ W2T,
    float* __restrict__ bq, float* __restrict__ bk, float* __restrict__ dsum)
{
  int gid = blockIdx.x * 256 + threadIdx.x;
  int idx = gid;
  if (idx < 512 * 512) {                       // WqT[j,k], j: qs|qe
    int j = idx >> 9, k = idx & 511;
    float v = (j < 256) ? Wqs[k * 256 + j] : Wqe[k * 256 + (j - 256)];
    WqT[idx] = f2bf(v);
  } else if ((idx -= 512 * 512) < 1024 * 512) { // WkT[j,k], j: ks|vs|ke|ve
    int j = idx >> 9, k = idx & 511;
    int s = j >> 8, jj = j & 255;
    const float* Wp = (s == 0) ? Wks : (s == 1) ? Wvs : (s == 2) ? Wke : Wve;
    WkT[idx] = f2bf(Wp[k * 256 + jj]);
  } else if ((idx -= 1024 * 512) < 256 * 1024) { // W1T[j,k]
    int j = idx >> 10, k = idx & 1023;
    W1T[idx] = f2bf(W1[k * 256 + j]);
  } else if ((idx -= 256 * 1024) < 256 * 256) {  // W2T[j,k]
    int j = idx >> 8, k = idx & 255;
    W2T[idx] = f2bf(W2[k * 256 + j]);
  }
  if (gid < 512)  bq[gid] = (gid < 256) ? bqs[gid] : bqe[gid - 256];
  if (gid < 1024) bk[gid] = (gid < 256) ? bks[gid]
                    : (gid < 512) ? bvs[gid - 256]
                    : (gid < 768) ? bke[gid - 512] : bve[gid - 768];
  if (gid < 8) dsum[gid] = 0.f;
}

// row sum-of-squares over 256 bf16 columns (one wave per row)
__global__ __launch_bounds__(256) void k_rowsq(
    const unsigned short* __restrict__ X, int stride, int colOff, float* __restrict__ out)
{
  int row = blockIdx.x * 4 + (threadIdx.x >> 6);
  int lane = threadIdx.x & 63;
  const unsigned short* p = X + (size_t)row * stride + colOff + lane * 4;
  uint2 u = *(const uint2*)p;
  float a0 = bf2f((unsigned short)(u.x & 0xffff));
  float a1 = bf2f((unsigned short)(u.x >> 16));
  float a2 = bf2f((unsigned short)(u.y & 0xffff));
  float a3 = bf2f((unsigned short)(u.y >> 16));
  float s = a0 * a0 + a1 * a1 + a2 * a2 + a3 * a3;
#pragma unroll
  for (int o = 32; o; o >>= 1) s += __shfl_down(s, o);
  if (lane == 0) out[row] = s;
}

// VT[b, j, m] = Xk[b*M+m, (j<256)?256+j:512+j]  (v_struct | v_elec transposed)
__global__ void k_trans_vt(const unsigned short* __restrict__ Xk, unsigned short* __restrict__ VT) {
  __shared__ unsigned short t[32][33];
  const int b = blockIdx.z;
  const int m0 = blockIdx.x * 32, j0 = blockIdx.y * 32;
  const int tx = threadIdx.x, ty = threadIdx.y;
#pragma unroll
  for (int i = 0; i < 4; i++) {
    int m = m0 + ty + i * 8;
    int j = j0 + tx;
    int c = (j < 256) ? (256 + j) : (512 + j);
    t[ty + i * 8][tx] = Xk[((size_t)b * Mk + m) * 1024 + c];
  }
  __syncthreads();
#pragma unroll
  for (int i = 0; i < 4; i++) {
    int j = j0 + ty + i * 8;
    int m = m0 + tx;
    VT[((size_t)b * 512 + j) * Mk + m] = t[tx][ty + i * 8];
  }
}

// fused = [ctx_s | ctx_e | ctx_s-ctx_e | ctx_s*ctx_e]
__global__ void k_fused(const unsigned short* __restrict__ ctx, unsigned short* __restrict__ fused) {
  int idx = blockIdx.x * 256 + threadIdx.x;
  int bn = idx >> 8;
  int j = idx & 255;
  float cs = bf2f(ctx[(size_t)bn * 512 + j]);
  float ce = bf2f(ctx[(size_t)bn * 512 + 256 + j]);
  size_t o = (size_t)bn * 1024 + j;
  fused[o]       = f2bf(cs);
  fused[o + 256] = f2bf(ce);
  fused[o + 512] = f2bf(cs - ce);
  fused[o + 768] = f2bf(cs * ce);
}

// ---------------------------------------------------------------------------
extern "C" void kernel_launch(void* const* d_in, const int* in_sizes, int n_in,
                              void* d_out, int out_size, void* d_ws, size_t ws_size,
                              hipStream_t stream) {
  (void)in_sizes; (void)n_in; (void)out_size; (void)ws_size;
  const float* q_fp  = (const float*)d_in[0];
  const float* v_ret = (const float*)d_in[1];
  const float* pi    = (const float*)d_in[2];
  const float* Wqs = (const float*)d_in[3];  const float* bqs = (const float*)d_in[4];
  const float* Wks = (const float*)d_in[5];  const float* bks = (const float*)d_in[6];
  const float* Wvs = (const float*)d_in[7];  const float* bvs = (const float*)d_in[8];
  const float* Wqe = (const float*)d_in[9];  const float* bqe = (const float*)d_in[10];
  const float* Wke = (const float*)d_in[11]; const float* bke = (const float*)d_in[12];
  const float* Wve = (const float*)d_in[13]; const float* bve = (const float*)d_in[14];
  const float* W1  = (const float*)d_in[15]; const float* b1  = (const float*)d_in[16];
  const float* W2  = (const float*)d_in[17]; const float* b2  = (const float*)d_in[18];
  const float* gamma = (const float*)d_in[19];
  const float* ew    = (const float*)d_in[20];

  char* w = (char*)d_ws;
  unsigned short* WqT = (unsigned short*)(w + 0);          // 512x512 bf16
  unsigned short* WkT = (unsigned short*)(w + 524288);     // 1024x512
  unsigned short* W1T = (unsigned short*)(w + 1572864);    // 256x1024
  unsigned short* W2T = (unsigned short*)(w + 2097152);    // 256x256
  float* bq   = (float*)(w + 2228224);                     // 512
  float* bk   = (float*)(w + 2230272);                     // 1024
  float* q2   = (float*)(w + 2234368);                     // 16384
  float* k2   = (float*)(w + 2299904);                     // 16384
  float* dsum = (float*)(w + 2365440);                     // 8
  unsigned short* ctx  = (unsigned short*)(w + 2365696);   // 16384x512 bf16 (16.8MB)
  unsigned short* hbuf = (unsigned short*)(w + 19142912);  // 16384x256 bf16 (8.4MB)
  unsigned short* Xq = (unsigned short*)(w + 35920128);    // 16384x512 (qs|qe)
  unsigned short* Xk = (unsigned short*)(w + 52697344);    // 16384x1024 (ks|vs|ke|ve)
  unsigned short* VT = (unsigned short*)(w + 86251776);    // 8x512x2048
  unsigned short* attn = (unsigned short*)(w + 103028992); // 16384x2048 bf16 unnorm
  unsigned short* fused = attn;                            // reuse (attn dead after PV)
  // sd chunk buffer (2 batches = exactly 32MiB) overlays ctx+hbuf, which are
  // dead until k_fused/MLP.
  unsigned* sdbuf = (unsigned*)(w + 2365696);
  float* rowsum = (float*)d_out;  // 64KB scratch in d_out; overwritten by final GEMM

  k_prep_w<<<4352, 256, 0, stream>>>(Wqs, Wqe, Wks, Wvs, Wke, Wve, W1, W2,
                                     bqs, bqe, bks, bvs, bke, bve,
                                     WqT, WkT, W1T, W2T, bq, bk, dsum);
  // projections straight from fp32 inputs: Xq=[q_struct|q_elec], Xk=[ks|vs|ke|ve]
  k_proj<<<dim3(128, 4), 256, 0, stream>>>(q_fp,  WqT, bq, Xq, 512, 512);
  k_proj<<<dim3(128, 8), 256, 0, stream>>>(v_ret, WkT, bk, Xk, 1024, 512);
  k_rowsq<<<4096, 256, 0, stream>>>(Xq, 512, 256, q2);
  k_rowsq<<<4096, 256, 0, stream>>>(Xk, 1024, 512, k2);
  // chunked (2 batches each): GEMMs once -> packed (s,d); then streaming softmax
  for (int c = 0; c < 4; ++c) {
    k_sd<<<dim3(16, 16, 2), 256, 0, stream>>>(Xq, Xk, q2, k2, 2 * c, dsum, sdbuf);
    k_softmax<<<1024, 256, 0, stream>>>(sdbuf, pi, dsum, gamma, ew, 2 * c,
                                        attn, rowsum);
  }
  // transpose v_struct/v_elec -> VT
  k_trans_vt<<<dim3(64, 16, 8), dim3(32, 8), 0, stream>>>(Xk, VT);
  // ctx = (attn @ [Vs|Ve]) / rowsum
  k_pv<<<dim3(16, 8, 8), 256, 0, stream>>>(attn, VT, rowsum, ctx);
  // fused features
  k_fused<<<16384, 256, 0, stream>>>(ctx, fused);
  // MLP: h = silu(fused @ W1 + b1); out = h @ W2 + b2 (fp32)
  k_gemm_bias<1><<<dim3(128, 2), 256, 0, stream>>>(fused, W1T, b1, hbuf, 256, 1024);
  k_gemm_bias<2><<<dim3(128, 2), 256, 0, stream>>>(hbuf, W2T, b2, d_out, 256, 256);
}

// Round 2
// 572.750 us; speedup vs baseline: 1.0187x; 1.0133x over previous
//
#include <hip/hip_runtime.h>

// PGWCrossAttention on MI355X (gfx950), bf16 MFMA pipeline.
// R7: global_load_lds(16B) staging for all bf16 GEMM cores (m97 recipe:
// 517->874 TF on this exact 128^2 tile). Wave-uniform LDS dest = contiguous
// 32-row stripe per wave, lane lands at base+lane*16B (linear, m104-safe).
// k_pv upped to 128x128 tiles (halves attn re-reads, K=2048 amortizes).
// k_proj keeps VGPR fp32->bf16 for A, gload_lds for B.
#define Bsz 8
#define Nq  2048
#define Mk  2048
#define BKt 32          // K-tile per MFMA step

typedef __attribute__((ext_vector_type(8))) short   short8;   // 8 bf16 (4 VGPRs)
typedef __attribute__((ext_vector_type(4))) float   floatx4;  // MFMA acc

__device__ __forceinline__ unsigned short f2bf(float f) {
  union { float f; unsigned u; } x; x.f = f;
  unsigned r = x.u + 0x7fffu + ((x.u >> 16) & 1u);   // RNE
  return (unsigned short)(r >> 16);
}
__device__ __forceinline__ float bf2f(unsigned short s) {
  union { unsigned u; float f; } x; x.u = ((unsigned)s) << 16;
  return x.f;
}

// async global->LDS, 16B per lane. LDS dest is wave-uniform base + lane*16.
__device__ __forceinline__ void gload16(const unsigned short* g, unsigned short* l) {
  __builtin_amdgcn_global_load_lds(
      (const __attribute__((address_space(1))) void*)g,
      (__attribute__((address_space(3))) void*)l, 16, 0, 0);
}

// ---------------------------------------------------------------------------
// NT GEMM core 128x128: C += A[128,K] . B[128,K]^T, fp32 acc, 2x2 waves,
// 4x4 16x16 frags/wave. Frag layout (m89/m91): A/B elem[m=lane&15][k=(lane>>4)*8+j];
// C/D: col=lane&15, row=(lane>>4)*4+reg.
// Staging: wave w stages rows [32w,32w+32) of A and B via 4 global_load_lds.
// Lane l of a load covers row base+(l>>2), col (l&3)*8 -> byte off l*16 (linear).
// ---------------------------------------------------------------------------
__device__ __forceinline__ void gemm_core_nt(
    const unsigned short* __restrict__ A, int lda,
    const unsigned short* __restrict__ B, int ldb,
    int K, unsigned short* ldsA, unsigned short* ldsB,
    floatx4 (&acc)[4][4])
{
  const int tid  = threadIdx.x;
  const int lane = tid & 63;
  const int wid  = tid >> 6;
  const int wm   = wid & 1;
  const int wn   = wid >> 1;
  const int fr   = lane & 15;
  const int fk   = (lane >> 4) << 3;
  const int lr   = lane >> 2;          // 0..15
  const int lc   = (lane & 3) << 3;    // 0/8/16/24
  const int r0   = wid << 5;           // 32 rows per wave

  const unsigned short* gA0 = A + (size_t)(r0 + lr) * lda + lc;
  const unsigned short* gA1 = gA0 + (size_t)16 * lda;
  const unsigned short* gB0 = B + (size_t)(r0 + lr) * ldb + lc;
  const unsigned short* gB1 = gB0 + (size_t)16 * ldb;
  unsigned short* lA0 = ldsA + (r0     ) * BKt;
  unsigned short* lA1 = ldsA + (r0 + 16) * BKt;
  unsigned short* lB0 = ldsB + (r0     ) * BKt;
  unsigned short* lB1 = ldsB + (r0 + 16) * BKt;
  const unsigned short* fa = ldsA + (wm * 64 + fr) * BKt + fk;
  const unsigned short* fb = ldsB + (wn * 64 + fr) * BKt + fk;

  for (int k0 = 0; k0 < K; k0 += BKt) {
    __syncthreads();                  // prior iter's frag reads done
    gload16(gA0, lA0); gA0 += BKt;
    gload16(gA1, lA1); gA1 += BKt;
    gload16(gB0, lB0); gB0 += BKt;
    gload16(gB1, lB1); gB1 += BKt;
    __syncthreads();                  // vmcnt(0) drained before barrier
    short8 af[4], bfr[4];
#pragma unroll
    for (int i = 0; i < 4; i++) af[i]  = *(const short8*)(fa + i * 16 * BKt);
#pragma unroll
    for (int i = 0; i < 4; i++) bfr[i] = *(const short8*)(fb + i * 16 * BKt);
#pragma unroll
    for (int i = 0; i < 4; i++)
#pragma unroll
      for (int j = 0; j < 4; j++)
        acc[i][j] = __builtin_amdgcn_mfma_f32_16x16x32_bf16(af[i], bfr[j], acc[i][j], 0, 0, 0);
  }
}

#define EPILOGUE_VARS \
  const int lane = threadIdx.x & 63; \
  const int wid  = threadIdx.x >> 6; \
  const int wm   = wid & 1; \
  const int wn   = wid >> 1; \
  const int r4   = (lane >> 4) * 4;  \
  const int cn   = lane & 15; \
  (void)wid;

// ---------------------------------------------------------------------------
// Projection GEMM, A in fp32 (bf16-cast during staging, VGPR path).
// B (bf16 weights) staged via global_load_lds. 128x128 tile.
// ---------------------------------------------------------------------------
__global__ __launch_bounds__(256, 2) void k_proj(
    const float* __restrict__ A, const unsigned short* __restrict__ Bw,
    const float* __restrict__ bias, unsigned short* __restrict__ Cout,
    int Ncols, int K)
{
  __shared__ alignas(16) unsigned short ldsA[128 * BKt];
  __shared__ alignas(16) unsigned short ldsB[128 * BKt];
  floatx4 acc[4][4];
#pragma unroll
  for (int i = 0; i < 4; i++)
#pragma unroll
    for (int j = 0; j < 4; j++)
#pragma unroll
      for (int t = 0; t < 4; t++) acc[i][j][t] = 0.f;

  const int tid = threadIdx.x;
  const int ar  = tid >> 1;            // A staging row 0..127
  const int ac  = (tid & 1) << 4;      // A staging col 0/16

  const int lane = tid & 63;
  const int wid  = tid >> 6;
  const int wm   = wid & 1;
  const int wn   = wid >> 1;
  const int fr   = lane & 15;
  const int fk   = (lane >> 4) << 3;
  const int lr   = lane >> 2;
  const int lc   = (lane & 3) << 3;
  const int r0   = wid << 5;

  const float* ap = A + ((size_t)blockIdx.x * 128 + ar) * K + ac;
  const unsigned short* gB0 = Bw + ((size_t)blockIdx.y * 128 + r0 + lr) * K + lc;
  const unsigned short* gB1 = gB0 + (size_t)16 * K;
  unsigned short* lB0 = ldsB + (r0     ) * BKt;
  unsigned short* lB1 = ldsB + (r0 + 16) * BKt;
  uint4* sa = (uint4*)(ldsA + ar * BKt + ac);
  const unsigned short* fa = ldsA + (wm * 64 + fr) * BKt + fk;
  const unsigned short* fb = ldsB + (wn * 64 + fr) * BKt + fk;

  for (int k0 = 0; k0 < K; k0 += BKt) {
    float4 f0 = *(const float4*)(ap + 0);
    float4 f1 = *(const float4*)(ap + 4);
    float4 f2 = *(const float4*)(ap + 8);
    float4 f3 = *(const float4*)(ap + 12);
    ap += BKt;
    uint4 pa, pb;
    pa.x = f2bf(f0.x) | ((unsigned)f2bf(f0.y) << 16);
    pa.y = f2bf(f0.z) | ((unsigned)f2bf(f0.w) << 16);
    pa.z = f2bf(f1.x) | ((unsigned)f2bf(f1.y) << 16);
    pa.w = f2bf(f1.z) | ((unsigned)f2bf(f1.w) << 16);
    pb.x = f2bf(f2.x) | ((unsigned)f2bf(f2.y) << 16);
    pb.y = f2bf(f2.z) | ((unsigned)f2bf(f2.w) << 16);
    pb.z = f2bf(f3.x) | ((unsigned)f2bf(f3.y) << 16);
    pb.w = f2bf(f3.z) | ((unsigned)f2bf(f3.w) << 16);
    __syncthreads();                  // prior frag reads done
    gload16(gB0, lB0); gB0 += BKt;
    gload16(gB1, lB1); gB1 += BKt;
    sa[0] = pa; sa[1] = pb;
    __syncthreads();                  // vmcnt+lgkm drained
    short8 af[4], bfr[4];
#pragma unroll
    for (int i = 0; i < 4; i++) af[i]  = *(const short8*)(fa + i * 16 * BKt);
#pragma unroll
    for (int i = 0; i < 4; i++) bfr[i] = *(const short8*)(fb + i * 16 * BKt);
#pragma unroll
    for (int i = 0; i < 4; i++)
#pragma unroll
      for (int j = 0; j < 4; j++)
        acc[i][j] = __builtin_amdgcn_mfma_f32_16x16x32_bf16(af[i], bfr[j], acc[i][j], 0, 0, 0);
  }

  const int r4 = (lane >> 4) * 4;
  const int cn = lane & 15;
#pragma unroll
  for (int i = 0; i < 4; i++) {
#pragma unroll
    for (int j = 0; j < 4; j++) {
      int gc = blockIdx.y * 128 + wn * 64 + j * 16 + cn;
      float bv = bias[gc];
#pragma unroll
      for (int r = 0; r < 4; r++) {
        int gr = blockIdx.x * 128 + wm * 64 + i * 16 + r4 + r;
        Cout[(size_t)gr * Ncols + gc] = f2bf(acc[i][j][r] + bv);
      }
    }
  }
}

// ---------------------------------------------------------------------------
// MLP GEMM (bf16 A). MODE 1: silu -> bf16. MODE 2: store fp32.
// ---------------------------------------------------------------------------
template<int MODE>
__global__ __launch_bounds__(256, 3) void k_gemm_bias(
    const unsigned short* __restrict__ A, const unsigned short* __restrict__ Bw,
    const float* __restrict__ bias, void* __restrict__ Cout, int Ncols, int K)
{
  __shared__ alignas(16) unsigned short ldsA[128 * BKt];
  __shared__ alignas(16) unsigned short ldsB[128 * BKt];
  floatx4 acc[4][4];
#pragma unroll
  for (int i = 0; i < 4; i++)
#pragma unroll
    for (int j = 0; j < 4; j++)
#pragma unroll
      for (int t = 0; t < 4; t++) acc[i][j][t] = 0.f;

  const unsigned short* Ab = A + (size_t)blockIdx.x * 128 * K;
  const unsigned short* Bb = Bw + (size_t)blockIdx.y * 128 * K;
  gemm_core_nt(Ab, K, Bb, K, K, ldsA, ldsB, acc);

  EPILOGUE_VARS
#pragma unroll
  for (int i = 0; i < 4; i++) {
#pragma unroll
    for (int j = 0; j < 4; j++) {
      int gc = blockIdx.y * 128 + wn * 64 + j * 16 + cn;
      float bv = bias[gc];
#pragma unroll
      for (int r = 0; r < 4; r++) {
        int gr = blockIdx.x * 128 + wm * 64 + i * 16 + r4 + r;
        float v = acc[i][j][r] + bv;
        if constexpr (MODE == 1) v = v / (1.f + __expf(-v));
        if constexpr (MODE == 2)
          ((float*)Cout)[(size_t)gr * Ncols + gc] = v;
        else
          ((unsigned short*)Cout)[(size_t)gr * Ncols + gc] = f2bf(v);
      }
    }
  }
}

// ---------------------------------------------------------------------------
// k_sd: struct + elec GEMMs at 128x128 tiles (each computed ONCE).
// Writes packed uint32 per element: lo = bf16(s * 0.0625), hi = bf16(d),
// accumulates dsum[b] (sum of d). sd buffer is chunk-local (2 batches).
// ---------------------------------------------------------------------------
__global__ __launch_bounds__(256, 2) void k_sd(
    const unsigned short* __restrict__ Xq, const unsigned short* __restrict__ Xk,
    const float* __restrict__ q2, const float* __restrict__ k2,
    int b0, float* __restrict__ dsum, unsigned* __restrict__ sd)
{
  __shared__ alignas(16) unsigned short ldsA[128 * BKt];
  __shared__ alignas(16) unsigned short ldsB[128 * BKt];
  floatx4 accS[4][4], accE[4][4];
#pragma unroll
  for (int i = 0; i < 4; i++)
#pragma unroll
    for (int j = 0; j < 4; j++)
#pragma unroll
      for (int t = 0; t < 4; t++) { accS[i][j][t] = 0.f; accE[i][j][t] = 0.f; }

  const int z = blockIdx.z;           // chunk-local batch 0/1
  const int b = b0 + z;
  const unsigned short* Aq = Xq + ((size_t)(b * Nq) + blockIdx.x * 128) * 512;
  const unsigned short* Bk = Xk + ((size_t)(b * Mk) + blockIdx.y * 128) * 1024;
  gemm_core_nt(Aq,       512, Bk,       1024, 256, ldsA, ldsB, accS);  // struct
  gemm_core_nt(Aq + 256, 512, Bk + 512, 1024, 256, ldsA, ldsB, accE);  // elec

  EPILOGUE_VARS
  float kkv[4];
#pragma unroll
  for (int j = 0; j < 4; j++)
    kkv[j] = k2[b * Mk + blockIdx.y * 128 + wn * 64 + j * 16 + cn];

  float lsum = 0.f;
#pragma unroll
  for (int i = 0; i < 4; i++) {
#pragma unroll
    for (int r = 0; r < 4; r++) {
      const int n = blockIdx.x * 128 + wm * 64 + i * 16 + r4 + r;
      const float qq = q2[b * Nq + n];
      unsigned* srow = sd + (size_t)(z * Nq + n) * Mk;
#pragma unroll
      for (int j = 0; j < 4; j++) {
        const int m = blockIdx.y * 128 + wn * 64 + j * 16 + cn;
        float d = sqrtf(fmaxf(qq + kkv[j] - 2.f * accE[i][j][r], 1e-12f));
        lsum += d;
        srow[m] = (unsigned)f2bf(accS[i][j][r] * 0.0625f)
                | ((unsigned)f2bf(d) << 16);
      }
    }
  }
#pragma unroll
  for (int o = 32; o; o >>= 1) lsum += __shfl_down(lsum, o);
  __syncthreads();                    // ldsA frag reads done before reuse
  float* red = (float*)ldsA;
  if (lane == 0) red[wid] = lsum;
  __syncthreads();
  if (threadIdx.x == 0) atomicAdd(dsum + b, red[0] + red[1] + red[2] + red[3]);
}

// ---------------------------------------------------------------------------
// k_softmax: streaming. One wave per row: e = exp(s - ew*d/scale) * pi^gamma,
// attn (bf16 unnorm) + rowsum[row] (direct store, no atomics). Fully coalesced.
// ---------------------------------------------------------------------------
__global__ __launch_bounds__(256) void k_softmax(
    const unsigned* __restrict__ sd, const float* __restrict__ pi,
    const float* __restrict__ dsum, const float* __restrict__ gamma_p,
    const float* __restrict__ ew_p, int b0,
    unsigned short* __restrict__ attn, float* __restrict__ rowsum)
{
  const int wid  = threadIdx.x >> 6;
  const int lane = threadIdx.x & 63;
  const int rl   = blockIdx.x * 4 + wid;     // chunk-local row 0..4095
  const int b    = b0 + (rl >> 11);
  const int n    = rl & 2047;

  const float scale = fmaxf(dsum[b] * (1.f / (2048.f * 2048.f)), 1e-4f);
  const float einv  = ew_p[0] / scale;
  const float gv    = gamma_p[0];
  const bool  g1    = (gv == 1.0f);          // wave-uniform fast path

  const unsigned*  sp = sd  + (size_t)rl * Mk;
  const float*     pp = pi  + ((size_t)b * Nq + n) * Mk;
  unsigned short*  ap = attn + ((size_t)b * Nq + n) * Mk;

  float rs = 0.f;
  for (int it = 0; it < 8; ++it) {
    const int c = it * 256 + lane * 4;
    const uint4  sv = *(const uint4*)(sp + c);
    const float4 pv = *(const float4*)(pp + c);
    const unsigned uu[4]  = {sv.x, sv.y, sv.z, sv.w};
    const float    pp4[4] = {pv.x, pv.y, pv.z, pv.w};
    float e[4];
#pragma unroll
    for (int t = 0; t < 4; ++t) {
      union { unsigned u; float f; } cs, cd;
      cs.u = uu[t] << 16;                    // s * 0.0625
      cd.u = uu[t] & 0xffff0000u;            // d
      float p  = fmaxf(pp4[t], 1e-9f);
      float pf = g1 ? p : __expf(gv * __logf(p));
      e[t] = __expf(cs.f - einv * cd.f) * pf;
      rs += e[t];
    }
    uint2 st;
    st.x = (unsigned)f2bf(e[0]) | ((unsigned)f2bf(e[1]) << 16);
    st.y = (unsigned)f2bf(e[2]) | ((unsigned)f2bf(e[3]) << 16);
    *(uint2*)(ap + c) = st;
  }
#pragma unroll
  for (int o = 32; o; o >>= 1) rs += __shfl_down(rs, o);
  if (lane == 0) rowsum[b * Nq + n] = rs;
}

// ---------------------------------------------------------------------------
// PV: ctx[b,n,gc] = (attn_unnorm @ [Vs|Ve]) / rowsum[n]. 128x128 tile (K=2048).
// ---------------------------------------------------------------------------
__global__ __launch_bounds__(256, 3) void k_pv(
    const unsigned short* __restrict__ At, const unsigned short* __restrict__ VT,
    const float* __restrict__ rowsum, unsigned short* __restrict__ ctx)
{
  __shared__ alignas(16) unsigned short ldsA[128 * BKt];
  __shared__ alignas(16) unsigned short ldsB[128 * BKt];
  floatx4 acc[4][4];
#pragma unroll
  for (int i = 0; i < 4; i++)
#pragma unroll
    for (int j = 0; j < 4; j++)
#pragma unroll
      for (int t = 0; t < 4; t++) acc[i][j][t] = 0.f;

  const int b = blockIdx.z;
  const unsigned short* Ab = At + ((size_t)b * Nq + blockIdx.x * 128) * (size_t)Mk;
  const unsigned short* Bb = VT + ((size_t)b * 512 + blockIdx.y * 128) * (size_t)Mk;
  gemm_core_nt(Ab, Mk, Bb, Mk, Mk, ldsA, ldsB, acc);

  EPILOGUE_VARS
  const int rowbase = b * Nq + blockIdx.x * 128 + wm * 64;
#pragma unroll
  for (int i = 0; i < 4; i++) {
    float rinv[4];
#pragma unroll
    for (int r = 0; r < 4; r++)
      rinv[r] = 1.f / rowsum[rowbase + i * 16 + r4 + r];
#pragma unroll
    for (int j = 0; j < 4; j++) {
      int gc = blockIdx.y * 128 + wn * 64 + j * 16 + cn;
#pragma unroll
      for (int r = 0; r < 4; r++) {
        int gr = blockIdx.x * 128 + wm * 64 + i * 16 + r4 + r;
        ctx[((size_t)b * Nq + gr) * 512 + gc] = f2bf(acc[i][j][r] * rinv[r]);
      }
    }
  }
}

// ---------------------------------------------------------------------------
// Small utility kernels
// ---------------------------------------------------------------------------
// transpose + concat weights -> bf16; concat biases; zero dsum
__global__ void k_prep_w(
    const float* __restrict__ Wqs, const float* __restrict__ Wqe,
    const float* __restrict__ Wks, const float* __restrict__ Wvs,
    const float* __restrict__ Wke, const float* __restrict__ Wve,
    const float* __restrict__ W1,  const float* __restrict__ W2,
    const float* __restrict__ bqs, const float* __restrict__ bqe,
    const float* __restrict__ bks, const float* __restrict__ bvs,
    const float* __restrict__ bke, const float* __restrict__ bve,
    unsigned short* __restrict__ WqT, unsigned short* __restrict__ WkT,
    unsigned short* __restrict__ W1T, unsigned short* __restrict__ W2T,
    float* __restrict__ bq, float* __restrict__ bk, float* __restrict__ dsum)
{
  int gid = blockIdx.x * 256 + threadIdx.x;
  int idx = gid;
  if (idx < 512 * 512) {                       // WqT[j,k], j: qs|qe
    int j = idx >> 9, k = idx & 511;
    float v = (j < 256) ? Wqs[k * 256 + j] : Wqe[k * 256 + (j - 256)];
    WqT[idx] = f2bf(v);
  } else if ((idx -= 512 * 512) < 1024 * 512) { // WkT[j,k], j: ks|vs|ke|ve
    int j = idx >> 9, k = idx & 511;
    int s = j >> 8, jj = j & 255;
    const float* Wp = (s == 0) ? Wks : (s == 1) ? Wvs : (s == 2) ? Wke : Wve;
    WkT[idx] = f2bf(Wp[k * 256 + jj]);
  } else if ((idx -= 1024 * 512) < 256 * 1024) { // W1T[j,k]
    int j = idx >> 10, k = idx & 1023;
    W1T[idx] = f2bf(W1[k * 256 + j]);
  } else if ((idx -= 256 * 1024) < 256 * 256) {  // W2T[j,k]
    int j = idx >> 8, k = idx & 255;
    W2T[idx] = f2bf(W2[k * 256 + j]);
  }
  if (gid < 512)  bq[gid] = (gid < 256) ? bqs[gid] : bqe[gid - 256];
  if (gid < 1024) bk[gid] = (gid < 256) ? bks[gid]
                    : (gid < 512) ? bvs[gid - 256]
                    : (gid < 768) ? bke[gid - 512] : bve[gid - 768];
  if (gid < 8) dsum[gid] = 0.f;
}

// row sum-of-squares over 256 bf16 columns (one wave per row)
__global__ __launch_bounds__(256) void k_rowsq(
    const unsigned short* __restrict__ X, int stride, int colOff, float* __restrict__ out)
{
  int row = blockIdx.x * 4 + (threadIdx.x >> 6);
  int lane = threadIdx.x & 63;
  const unsigned short* p = X + (size_t)row * stride + colOff + lane * 4;
  uint2 u = *(const uint2*)p;
  float a0 = bf2f((unsigned short)(u.x & 0xffff));
  float a1 = bf2f((unsigned short)(u.x >> 16));
  float a2 = bf2f((unsigned short)(u.y & 0xffff));
  float a3 = bf2f((unsigned short)(u.y >> 16));
  float s = a0 * a0 + a1 * a1 + a2 * a2 + a3 * a3;
#pragma unroll
  for (int o = 32; o; o >>= 1) s += __shfl_down(s, o);
  if (lane == 0) out[row] = s;
}

// VT[b, j, m] = Xk[b*M+m, (j<256)?256+j:512+j]  (v_struct | v_elec transposed)
__global__ void k_trans_vt(const unsigned short* __restrict__ Xk, unsigned short* __restrict__ VT) {
  __shared__ unsigned short t[32][33];
  const int b = blockIdx.z;
  const int m0 = blockIdx.x * 32, j0 = blockIdx.y * 32;
  const int tx = threadIdx.x, ty = threadIdx.y;
#pragma unroll
  for (int i = 0; i < 4; i++) {
    int m = m0 + ty + i * 8;
    int j = j0 + tx;
    int c = (j < 256) ? (256 + j) : (512 + j);
    t[ty + i * 8][tx] = Xk[((size_t)b * Mk + m) * 1024 + c];
  }
  __syncthreads();
#pragma unroll
  for (int i = 0; i < 4; i++) {
    int j = j0 + ty + i * 8;
    int m = m0 + tx;
    VT[((size_t)b * 512 + j) * Mk + m] = t[tx][ty + i * 8];
  }
}

// fused = [ctx_s | ctx_e | ctx_s-ctx_e | ctx_s*ctx_e]
__global__ void k_fused(const unsigned short* __restrict__ ctx, unsigned short* __restrict__ fused) {
  int idx = blockIdx.x * 256 + threadIdx.x;
  int bn = idx >> 8;
  int j = idx & 255;
  float cs = bf2f(ctx[(size_t)bn * 512 + j]);
  float ce = bf2f(ctx[(size_t)bn * 512 + 256 + j]);
  size_t o = (size_t)bn * 1024 + j;
  fused[o]       = f2bf(cs);
  fused[o + 256] = f2bf(ce);
  fused[o + 512] = f2bf(cs - ce);
  fused[o + 768] = f2bf(cs * ce);
}

// ---------------------------------------------------------------------------
extern "C" void kernel_launch(void* const* d_in, const int* in_sizes, int n_in,
                              void* d_out, int out_size, void* d_ws, size_t ws_size,
                              hipStream_t stream) {
  (void)in_sizes; (void)n_in; (void)out_size; (void)ws_size;
  const float* q_fp  = (const float*)d_in[0];
  const float* v_ret = (const float*)d_in[1];
  const float* pi    = (const float*)d_in[2];
  const float* Wqs = (const float*)d_in[3];  const float* bqs = (const float*)d_in[4];
  const float* Wks = (const float*)d_in[5];  const float* bks = (const float*)d_in[6];
  const float* Wvs = (const float*)d_in[7];  const float* bvs = (const float*)d_in[8];
  const float* Wqe = (const float*)d_in[9];  const float* bqe = (const float*)d_in[10];
  const float* Wke = (const float*)d_in[11]; const float* bke = (const float*)d_in[12];
  const float* Wve = (const float*)d_in[13]; const float* bve = (const float*)d_in[14];
  const float* W1  = (const float*)d_in[15]; const float* b1  = (const float*)d_in[16];
  const float* W2  = (const float*)d_in[17]; const float* b2  = (const float*)d_in[18];
  const float* gamma = (const float*)d_in[19];
  const float* ew    = (const float*)d_in[20];

  char* w = (char*)d_ws;
  unsigned short* WqT = (unsigned short*)(w + 0);          // 512x512 bf16
  unsigned short* WkT = (unsigned short*)(w + 524288);     // 1024x512
  unsigned short* W1T = (unsigned short*)(w + 1572864);    // 256x1024
  unsigned short* W2T = (unsigned short*)(w + 2097152);    // 256x256
  float* bq   = (float*)(w + 2228224);                     // 512
  float* bk   = (float*)(w + 2230272);                     // 1024
  float* q2   = (float*)(w + 2234368);                     // 16384
  float* k2   = (float*)(w + 2299904);                     // 16384
  float* dsum = (float*)(w + 2365440);                     // 8
  unsigned short* ctx  = (unsigned short*)(w + 2365696);   // 16384x512 bf16 (16.8MB)
  unsigned short* hbuf = (unsigned short*)(w + 19142912);  // 16384x256 bf16 (8.4MB)
  unsigned short* Xq = (unsigned short*)(w + 35920128);    // 16384x512 (qs|qe)
  unsigned short* Xk = (unsigned short*)(w + 52697344);    // 16384x1024 (ks|vs|ke|ve)
  unsigned short* VT = (unsigned short*)(w + 86251776);    // 8x512x2048
  unsigned short* attn = (unsigned short*)(w + 103028992); // 16384x2048 bf16 unnorm
  unsigned short* fused = attn;                            // reuse (attn dead after PV)
  // sd chunk buffer (2 batches = exactly 32MiB) overlays ctx+hbuf, which are
  // dead until k_fused/MLP.
  unsigned* sdbuf = (unsigned*)(w + 2365696);
  float* rowsum = (float*)d_out;  // 64KB scratch in d_out; overwritten by final GEMM

  k_prep_w<<<4352, 256, 0, stream>>>(Wqs, Wqe, Wks, Wvs, Wke, Wve, W1, W2,
                                     bqs, bqe, bks, bvs, bke, bve,
                                     WqT, WkT, W1T, W2T, bq, bk, dsum);
  // projections straight from fp32 inputs: Xq=[q_struct|q_elec], Xk=[ks|vs|ke|ve]
  k_proj<<<dim3(128, 4), 256, 0, stream>>>(q_fp,  WqT, bq, Xq, 512, 512);
  k_proj<<<dim3(128, 8), 256, 0, stream>>>(v_ret, WkT, bk, Xk, 1024, 512);
  k_rowsq<<<4096, 256, 0, stream>>>(Xq, 512, 256, q2);
  k_rowsq<<<4096, 256, 0, stream>>>(Xk, 1024, 512, k2);
  // chunked (2 batches each): GEMMs once -> packed (s,d); then streaming softmax
  for (int c = 0; c < 4; ++c) {
    k_sd<<<dim3(16, 16, 2), 256, 0, stream>>>(Xq, Xk, q2, k2, 2 * c, dsum, sdbuf);
    k_softmax<<<1024, 256, 0, stream>>>(sdbuf, pi, dsum, gamma, ew, 2 * c,
                                        attn, rowsum);
  }
  // transpose v_struct/v_elec -> VT
  k_trans_vt<<<dim3(64, 16, 8), dim3(32, 8), 0, stream>>>(Xk, VT);
  // ctx = (attn @ [Vs|Ve]) / rowsum
  k_pv<<<dim3(16, 4, 8), 256, 0, stream>>>(attn, VT, rowsum, ctx);
  // fused features
  k_fused<<<16384, 256, 0, stream>>>(ctx, fused);
  // MLP: h = silu(fused @ W1 + b1); out = h @ W2 + b2 (fp32)
  k_gemm_bias<1><<<dim3(128, 2), 256, 0, stream>>>(fused, W1T, b1, hbuf, 256, 1024);
  k_gemm_bias<2><<<dim3(128, 2), 256, 0, stream>>>(hbuf, W2T, b2, d_out, 256, 256);
}

// Round 3
// 567.508 us; speedup vs baseline: 1.0281x; 1.0092x over previous
//
#include <hip/hip_runtime.h>

// PGWCrossAttention on MI355X (gfx950), bf16 MFMA pipeline.
// R8: occupancy. Grid sizes (512 blocks) cap co-residency at 2 blocks/CU, so
// 256-thr blocks give only 8 waves/CU (2/SIMD) on the heavy kernels (m132:
// 2 vs 3 blocks/CU = 508 vs 874 TF). Fix: 8-wave (512-thr) 128^2 core, wave
// tile 64x32, acc[4][2] -> 16 waves/CU (4/SIMD) at the same grid.
// k_pv adds XCD swizzle (T1): per-z 64 blocks, lg=(l&7)*8+l/8 -> each XCD gets
// 2 attn row-panels x all 4 col-tiles (~3MB < 4MiB L2) -> attn re-reads L2-hit.
#define Bsz 8
#define Nq  2048
#define Mk  2048
#define BKt 32          // K-tile per MFMA step

typedef __attribute__((ext_vector_type(8))) short   short8;   // 8 bf16 (4 VGPRs)
typedef __attribute__((ext_vector_type(4))) float   floatx4;  // MFMA acc

__device__ __forceinline__ unsigned short f2bf(float f) {
  union { float f; unsigned u; } x; x.f = f;
  unsigned r = x.u + 0x7fffu + ((x.u >> 16) & 1u);   // RNE
  return (unsigned short)(r >> 16);
}
__device__ __forceinline__ float bf2f(unsigned short s) {
  union { unsigned u; float f; } x; x.u = ((unsigned)s) << 16;
  return x.f;
}

// async global->LDS, 16B per lane. LDS dest is wave-uniform base + lane*16.
__device__ __forceinline__ void gload16(const unsigned short* g, unsigned short* l) {
  __builtin_amdgcn_global_load_lds(
      (const __attribute__((address_space(1))) void*)g,
      (__attribute__((address_space(3))) void*)l, 16, 0, 0);
}

// ---------------------------------------------------------------------------
// 8-wave NT GEMM core 128x128: C += A[128,K] . B[128,K]^T. 512 threads,
// waves 2x4, wave tile 64x32, acc[4][2] = 32 regs/lane per GEMM.
// Staging: wave w stages rows [16w,16w+16) of A and B via 2 global_load_lds
// (lane l -> row base+(l>>2), col (l&3)*8 = byte off l*16, linear, m104-safe).
// Frag layout (m89/m91): A/B elem[m=lane&15][k=(lane>>4)*8+j];
// C/D: col=lane&15, row=(lane>>4)*4+reg.
// ---------------------------------------------------------------------------
__device__ __forceinline__ void gemm_core8_nt(
    const unsigned short* __restrict__ A, int lda,
    const unsigned short* __restrict__ B, int ldb,
    int K, unsigned short* ldsA, unsigned short* ldsB,
    floatx4 (&acc)[4][2])
{
  const int tid  = threadIdx.x;
  const int lane = tid & 63;
  const int wid  = tid >> 6;          // 0..7
  const int wm   = wid & 1;
  const int wn   = wid >> 1;          // 0..3
  const int fr   = lane & 15;
  const int fk   = (lane >> 4) << 3;
  const int lr   = lane >> 2;         // 0..15
  const int lc   = (lane & 3) << 3;   // 0/8/16/24
  const int r0   = wid << 4;          // 16 rows per wave

  const unsigned short* gA = A + (size_t)(r0 + lr) * lda + lc;
  const unsigned short* gB = B + (size_t)(r0 + lr) * ldb + lc;
  unsigned short* lA = ldsA + r0 * BKt;
  unsigned short* lB = ldsB + r0 * BKt;
  const unsigned short* fa = ldsA + (wm * 64 + fr) * BKt + fk;
  const unsigned short* fb = ldsB + (wn * 32 + fr) * BKt + fk;

  for (int k0 = 0; k0 < K; k0 += BKt) {
    __syncthreads();                  // prior iter's frag reads done
    gload16(gA, lA); gA += BKt;
    gload16(gB, lB); gB += BKt;
    __syncthreads();                  // vmcnt(0) drained before barrier
    short8 af[4], bfr[2];
#pragma unroll
    for (int i = 0; i < 4; i++) af[i]  = *(const short8*)(fa + i * 16 * BKt);
#pragma unroll
    for (int j = 0; j < 2; j++) bfr[j] = *(const short8*)(fb + j * 16 * BKt);
#pragma unroll
    for (int i = 0; i < 4; i++)
#pragma unroll
      for (int j = 0; j < 2; j++)
        acc[i][j] = __builtin_amdgcn_mfma_f32_16x16x32_bf16(af[i], bfr[j], acc[i][j], 0, 0, 0);
  }
}

#define EPILOGUE_VARS \
  const int lane = threadIdx.x & 63; \
  const int wid  = threadIdx.x >> 6; \
  const int wm   = wid & 1; \
  const int wn   = wid >> 1; \
  const int r4   = (lane >> 4) * 4;  \
  const int cn   = lane & 15; \
  (void)wid;

// ---------------------------------------------------------------------------
// Projection GEMM, A in fp32 (bf16-cast during staging, VGPR path).
// B (bf16 weights) staged via global_load_lds. 128x128 tile, 8 waves.
// ---------------------------------------------------------------------------
__global__ __launch_bounds__(512, 4) void k_proj(
    const float* __restrict__ A, const unsigned short* __restrict__ Bw,
    const float* __restrict__ bias, unsigned short* __restrict__ Cout,
    int Ncols, int K)
{
  __shared__ alignas(16) unsigned short ldsA[128 * BKt];
  __shared__ alignas(16) unsigned short ldsB[128 * BKt];
  floatx4 acc[4][2];
#pragma unroll
  for (int i = 0; i < 4; i++)
#pragma unroll
    for (int j = 0; j < 2; j++)
#pragma unroll
      for (int t = 0; t < 4; t++) acc[i][j][t] = 0.f;

  const int tid  = threadIdx.x;
  const int lane = tid & 63;
  const int wid  = tid >> 6;
  const int wm   = wid & 1;
  const int wn   = wid >> 1;
  const int fr   = lane & 15;
  const int fk   = (lane >> 4) << 3;
  const int lr   = lane >> 2;
  const int lc   = (lane & 3) << 3;
  const int r0   = wid << 4;

  const float* ap = A + ((size_t)blockIdx.x * 128 + r0 + lr) * K + lc;
  const unsigned short* gB = Bw + ((size_t)blockIdx.y * 128 + r0 + lr) * K + lc;
  unsigned short* lB = ldsB + r0 * BKt;
  uint4* sa = (uint4*)(ldsA + (r0 + lr) * BKt + lc);
  const unsigned short* fa = ldsA + (wm * 64 + fr) * BKt + fk;
  const unsigned short* fb = ldsB + (wn * 32 + fr) * BKt + fk;

  for (int k0 = 0; k0 < K; k0 += BKt) {
    float4 f0 = *(const float4*)(ap + 0);
    float4 f1 = *(const float4*)(ap + 4);
    ap += BKt;
    uint4 pa;
    pa.x = f2bf(f0.x) | ((unsigned)f2bf(f0.y) << 16);
    pa.y = f2bf(f0.z) | ((unsigned)f2bf(f0.w) << 16);
    pa.z = f2bf(f1.x) | ((unsigned)f2bf(f1.y) << 16);
    pa.w = f2bf(f1.z) | ((unsigned)f2bf(f1.w) << 16);
    __syncthreads();                  // prior frag reads done
    gload16(gB, lB); gB += BKt;
    *sa = pa;
    __syncthreads();                  // vmcnt+lgkm drained
    short8 af[4], bfr[2];
#pragma unroll
    for (int i = 0; i < 4; i++) af[i]  = *(const short8*)(fa + i * 16 * BKt);
#pragma unroll
    for (int j = 0; j < 2; j++) bfr[j] = *(const short8*)(fb + j * 16 * BKt);
#pragma unroll
    for (int i = 0; i < 4; i++)
#pragma unroll
      for (int j = 0; j < 2; j++)
        acc[i][j] = __builtin_amdgcn_mfma_f32_16x16x32_bf16(af[i], bfr[j], acc[i][j], 0, 0, 0);
  }

  const int r4 = (lane >> 4) * 4;
  const int cn = lane & 15;
#pragma unroll
  for (int i = 0; i < 4; i++) {
#pragma unroll
    for (int j = 0; j < 2; j++) {
      int gc = blockIdx.y * 128 + wn * 32 + j * 16 + cn;
      float bv = bias[gc];
#pragma unroll
      for (int r = 0; r < 4; r++) {
        int gr = blockIdx.x * 128 + wm * 64 + i * 16 + r4 + r;
        Cout[(size_t)gr * Ncols + gc] = f2bf(acc[i][j][r] + bv);
      }
    }
  }
}

// ---------------------------------------------------------------------------
// MLP GEMM (bf16 A), 8-wave. MODE 1: silu -> bf16. MODE 2: store fp32.
// ---------------------------------------------------------------------------
template<int MODE>
__global__ __launch_bounds__(512, 4) void k_gemm_bias(
    const unsigned short* __restrict__ A, const unsigned short* __restrict__ Bw,
    const float* __restrict__ bias, void* __restrict__ Cout, int Ncols, int K)
{
  __shared__ alignas(16) unsigned short ldsA[128 * BKt];
  __shared__ alignas(16) unsigned short ldsB[128 * BKt];
  floatx4 acc[4][2];
#pragma unroll
  for (int i = 0; i < 4; i++)
#pragma unroll
    for (int j = 0; j < 2; j++)
#pragma unroll
      for (int t = 0; t < 4; t++) acc[i][j][t] = 0.f;

  const unsigned short* Ab = A + (size_t)blockIdx.x * 128 * K;
  const unsigned short* Bb = Bw + (size_t)blockIdx.y * 128 * K;
  gemm_core8_nt(Ab, K, Bb, K, K, ldsA, ldsB, acc);

  EPILOGUE_VARS
#pragma unroll
  for (int i = 0; i < 4; i++) {
#pragma unroll
    for (int j = 0; j < 2; j++) {
      int gc = blockIdx.y * 128 + wn * 32 + j * 16 + cn;
      float bv = bias[gc];
#pragma unroll
      for (int r = 0; r < 4; r++) {
        int gr = blockIdx.x * 128 + wm * 64 + i * 16 + r4 + r;
        float v = acc[i][j][r] + bv;
        if constexpr (MODE == 1) v = v / (1.f + __expf(-v));
        if constexpr (MODE == 2)
          ((float*)Cout)[(size_t)gr * Ncols + gc] = v;
        else
          ((unsigned short*)Cout)[(size_t)gr * Ncols + gc] = f2bf(v);
      }
    }
  }
}

// ---------------------------------------------------------------------------
// k_sd: struct + elec GEMMs at 128x128 tiles (each computed ONCE), 8 waves.
// accS+accE = 64 regs/lane (was 128). Writes packed uint32 per element:
// lo = bf16(s * 0.0625), hi = bf16(d), accumulates dsum[b].
// ---------------------------------------------------------------------------
__global__ __launch_bounds__(512, 4) void k_sd(
    const unsigned short* __restrict__ Xq, const unsigned short* __restrict__ Xk,
    const float* __restrict__ q2, const float* __restrict__ k2,
    int b0, float* __restrict__ dsum, unsigned* __restrict__ sd)
{
  __shared__ alignas(16) unsigned short ldsA[128 * BKt];
  __shared__ alignas(16) unsigned short ldsB[128 * BKt];
  floatx4 accS[4][2], accE[4][2];
#pragma unroll
  for (int i = 0; i < 4; i++)
#pragma unroll
    for (int j = 0; j < 2; j++)
#pragma unroll
      for (int t = 0; t < 4; t++) { accS[i][j][t] = 0.f; accE[i][j][t] = 0.f; }

  const int z = blockIdx.z;           // chunk-local batch 0/1
  const int b = b0 + z;
  const unsigned short* Aq = Xq + ((size_t)(b * Nq) + blockIdx.x * 128) * 512;
  const unsigned short* Bk = Xk + ((size_t)(b * Mk) + blockIdx.y * 128) * 1024;
  gemm_core8_nt(Aq,       512, Bk,       1024, 256, ldsA, ldsB, accS);  // struct
  gemm_core8_nt(Aq + 256, 512, Bk + 512, 1024, 256, ldsA, ldsB, accE);  // elec

  EPILOGUE_VARS
  const int colT = blockIdx.y * 128 + wn * 32;
  const float kk0 = k2[b * Mk + colT + cn];
  const float kk1 = k2[b * Mk + colT + 16 + cn];

  float lsum = 0.f;
#pragma unroll
  for (int i = 0; i < 4; i++) {
#pragma unroll
    for (int r = 0; r < 4; r++) {
      const int n = blockIdx.x * 128 + wm * 64 + i * 16 + r4 + r;
      const float qq = q2[b * Nq + n];
      unsigned* srow = sd + (size_t)(z * Nq + n) * Mk;
#pragma unroll
      for (int j = 0; j < 2; j++) {
        const int m = colT + j * 16 + cn;
        float d = sqrtf(fmaxf(qq + (j ? kk1 : kk0) - 2.f * accE[i][j][r], 1e-12f));
        lsum += d;
        srow[m] = (unsigned)f2bf(accS[i][j][r] * 0.0625f)
                | ((unsigned)f2bf(d) << 16);
      }
    }
  }
#pragma unroll
  for (int o = 32; o; o >>= 1) lsum += __shfl_down(lsum, o);
  __syncthreads();                    // LDS frag reads done before reuse
  float* red = (float*)ldsA;
  if (lane == 0) red[wid] = lsum;
  __syncthreads();
  if (threadIdx.x == 0) {
    float s = 0.f;
#pragma unroll
    for (int t = 0; t < 8; t++) s += red[t];
    atomicAdd(dsum + b, s);
  }
}

// ---------------------------------------------------------------------------
// k_softmax: streaming. One wave per row: e = exp(s - ew*d/scale) * pi^gamma,
// attn (bf16 unnorm) + rowsum[row] (direct store, no atomics). Fully coalesced.
// ---------------------------------------------------------------------------
__global__ __launch_bounds__(256) void k_softmax(
    const unsigned* __restrict__ sd, const float* __restrict__ pi,
    const float* __restrict__ dsum, const float* __restrict__ gamma_p,
    const float* __restrict__ ew_p, int b0,
    unsigned short* __restrict__ attn, float* __restrict__ rowsum)
{
  const int wid  = threadIdx.x >> 6;
  const int lane = threadIdx.x & 63;
  const int rl   = blockIdx.x * 4 + wid;     // chunk-local row 0..4095
  const int b    = b0 + (rl >> 11);
  const int n    = rl & 2047;

  const float scale = fmaxf(dsum[b] * (1.f / (2048.f * 2048.f)), 1e-4f);
  const float einv  = ew_p[0] / scale;
  const float gv    = gamma_p[0];
  const bool  g1    = (gv == 1.0f);          // wave-uniform fast path

  const unsigned*  sp = sd  + (size_t)rl * Mk;
  const float*     pp = pi  + ((size_t)b * Nq + n) * Mk;
  unsigned short*  ap = attn + ((size_t)b * Nq + n) * Mk;

  float rs = 0.f;
  for (int it = 0; it < 8; ++it) {
    const int c = it * 256 + lane * 4;
    const uint4  sv = *(const uint4*)(sp + c);
    const float4 pv = *(const float4*)(pp + c);
    const unsigned uu[4]  = {sv.x, sv.y, sv.z, sv.w};
    const float    pp4[4] = {pv.x, pv.y, pv.z, pv.w};
    float e[4];
#pragma unroll
    for (int t = 0; t < 4; ++t) {
      union { unsigned u; float f; } cs, cd;
      cs.u = uu[t] << 16;                    // s * 0.0625
      cd.u = uu[t] & 0xffff0000u;            // d
      float p  = fmaxf(pp4[t], 1e-9f);
      float pf = g1 ? p : __expf(gv * __logf(p));
      e[t] = __expf(cs.f - einv * cd.f) * pf;
      rs += e[t];
    }
    uint2 st;
    st.x = (unsigned)f2bf(e[0]) | ((unsigned)f2bf(e[1]) << 16);
    st.y = (unsigned)f2bf(e[2]) | ((unsigned)f2bf(e[3]) << 16);
    *(uint2*)(ap + c) = st;
  }
#pragma unroll
  for (int o = 32; o; o >>= 1) rs += __shfl_down(rs, o);
  if (lane == 0) rowsum[b * Nq + n] = rs;
}

// ---------------------------------------------------------------------------
// PV: ctx[b,n,gc] = (attn_unnorm @ [Vs|Ve]) / rowsum[n]. 128x128 tile, 8 waves.
// XCD swizzle: per-z 64 blocks; lg = (l&7)*8 + l/8 -> XCD c gets row-tiles
// {2c,2c+1} x all 4 col-tiles (attn panels L2-resident, ~3MB/XCD).
// ---------------------------------------------------------------------------
__global__ __launch_bounds__(512, 4) void k_pv(
    const unsigned short* __restrict__ At, const unsigned short* __restrict__ VT,
    const float* __restrict__ rowsum, unsigned short* __restrict__ ctx)
{
  __shared__ alignas(16) unsigned short ldsA[128 * BKt];
  __shared__ alignas(16) unsigned short ldsB[128 * BKt];
  floatx4 acc[4][2];
#pragma unroll
  for (int i = 0; i < 4; i++)
#pragma unroll
    for (int j = 0; j < 2; j++)
#pragma unroll
      for (int t = 0; t < 4; t++) acc[i][j][t] = 0.f;

  const int l  = blockIdx.x;            // 0..63
  const int lg = ((l & 7) << 3) | (l >> 3);
  const int tx = lg >> 2;               // row tile 0..15
  const int ty = lg & 3;                // col tile 0..3
  const int b  = blockIdx.z;
  const unsigned short* Ab = At + ((size_t)b * Nq + tx * 128) * (size_t)Mk;
  const unsigned short* Bb = VT + ((size_t)b * 512 + ty * 128) * (size_t)Mk;
  gemm_core8_nt(Ab, Mk, Bb, Mk, Mk, ldsA, ldsB, acc);

  EPILOGUE_VARS
  const int rowbase = b * Nq + tx * 128 + wm * 64;
#pragma unroll
  for (int i = 0; i < 4; i++) {
    float rinv[4];
#pragma unroll
    for (int r = 0; r < 4; r++)
      rinv[r] = 1.f / rowsum[rowbase + i * 16 + r4 + r];
#pragma unroll
    for (int j = 0; j < 2; j++) {
      int gc = ty * 128 + wn * 32 + j * 16 + cn;
#pragma unroll
      for (int r = 0; r < 4; r++) {
        int gr = tx * 128 + wm * 64 + i * 16 + r4 + r;
        ctx[((size_t)b * Nq + gr) * 512 + gc] = f2bf(acc[i][j][r] * rinv[r]);
      }
    }
  }
}

// ---------------------------------------------------------------------------
// Small utility kernels
// ---------------------------------------------------------------------------
// transpose + concat weights -> bf16; concat biases; zero dsum
__global__ void k_prep_w(
    const float* __restrict__ Wqs, const float* __restrict__ Wqe,
    const float* __restrict__ Wks, const float* __restrict__ Wvs,
    const float* __restrict__ Wke, const float* __restrict__ Wve,
    const float* __restrict__ W1,  const float* __restrict__ W2,
    const float* __restrict__ bqs, const float* __restrict__ bqe,
    const float* __restrict__ bks, const float* __restrict__ bvs,
    const float* __restrict__ bke, const float* __restrict__ bve,
    unsigned short* __restrict__ WqT, unsigned short* __restrict__ WkT,
    unsigned short* __restrict__ W1T, unsigned short* __restrict__ W2T,
    float* __restrict__ bq, float* __restrict__ bk, float* __restrict__ dsum)
{
  int gid = blockIdx.x * 256 + threadIdx.x;
  int idx = gid;
  if (idx < 512 * 512) {                       // WqT[j,k], j: qs|qe
    int j = idx >> 9, k = idx & 511;
    float v = (j < 256) ? Wqs[k * 256 + j] : Wqe[k * 256 + (j - 256)];
    WqT[idx] = f2bf(v);
  } else if ((idx -= 512 * 512) < 1024 * 512) { // WkT[j,k], j: ks|vs|ke|ve
    int j = idx >> 9, k = idx & 511;
    int s = j >> 8, jj = j & 255;
    const float* Wp = (s == 0) ? Wks : (s == 1) ? Wvs : (s == 2) ? Wke : Wve;
    WkT[idx] = f2bf(Wp[k * 256 + jj]);
  } else if ((idx -= 1024 * 512) < 256 * 1024) { // W1T[j,k]
    int j = idx >> 10, k = idx & 1023;
    W1T[idx] = f2bf(W1[k * 256 + j]);
  } else if ((idx -= 256 * 1024) < 256 * 256) {  // W2T[j,k]
    int j = idx >> 8, k = idx & 255;
    W2T[idx] = f2bf(W2[k * 256 + j]);
  }
  if (gid < 512)  bq[gid] = (gid < 256) ? bqs[gid] : bqe[gid - 256];
  if (gid < 1024) bk[gid] = (gid < 256) ? bks[gid]
                    : (gid < 512) ? bvs[gid - 256]
                    : (gid < 768) ? bke[gid - 512] : bve[gid - 768];
  if (gid < 8) dsum[gid] = 0.f;
}

// row sum-of-squares over 256 bf16 columns (one wave per row)
__global__ __launch_bounds__(256) void k_rowsq(
    const unsigned short* __restrict__ X, int stride, int colOff, float* __restrict__ out)
{
  int row = blockIdx.x * 4 + (threadIdx.x >> 6);
  int lane = threadIdx.x & 63;
  const unsigned short* p = X + (size_t)row * stride + colOff + lane * 4;
  uint2 u = *(const uint2*)p;
  float a0 = bf2f((unsigned short)(u.x & 0xffff));
  float a1 = bf2f((unsigned short)(u.x >> 16));
  float a2 = bf2f((unsigned short)(u.y & 0xffff));
  float a3 = bf2f((unsigned short)(u.y >> 16));
  float s = a0 * a0 + a1 * a1 + a2 * a2 + a3 * a3;
#pragma unroll
  for (int o = 32; o; o >>= 1) s += __shfl_down(s, o);
  if (lane == 0) out[row] = s;
}

// VT[b, j, m] = Xk[b*M+m, (j<256)?256+j:512+j]  (v_struct | v_elec transposed)
__global__ void k_trans_vt(const unsigned short* __restrict__ Xk, unsigned short* __restrict__ VT) {
  __shared__ unsigned short t[32][33];
  const int b = blockIdx.z;
  const int m0 = blockIdx.x * 32, j0 = blockIdx.y * 32;
  const int tx = threadIdx.x, ty = threadIdx.y;
#pragma unroll
  for (int i = 0; i < 4; i++) {
    int m = m0 + ty + i * 8;
    int j = j0 + tx;
    int c = (j < 256) ? (256 + j) : (512 + j);
    t[ty + i * 8][tx] = Xk[((size_t)b * Mk + m) * 1024 + c];
  }
  __syncthreads();
#pragma unroll
  for (int i = 0; i < 4; i++) {
    int j = j0 + ty + i * 8;
    int m = m0 + tx;
    VT[((size_t)b * 512 + j) * Mk + m] = t[tx][ty + i * 8];
  }
}

// fused = [ctx_s | ctx_e | ctx_s-ctx_e | ctx_s*ctx_e]
__global__ void k_fused(const unsigned short* __restrict__ ctx, unsigned short* __restrict__ fused) {
  int idx = blockIdx.x * 256 + threadIdx.x;
  int bn = idx >> 8;
  int j = idx & 255;
  float cs = bf2f(ctx[(size_t)bn * 512 + j]);
  float ce = bf2f(ctx[(size_t)bn * 512 + 256 + j]);
  size_t o = (size_t)bn * 1024 + j;
  fused[o]       = f2bf(cs);
  fused[o + 256] = f2bf(ce);
  fused[o + 512] = f2bf(cs - ce);
  fused[o + 768] = f2bf(cs * ce);
}

// ---------------------------------------------------------------------------
extern "C" void kernel_launch(void* const* d_in, const int* in_sizes, int n_in,
                              void* d_out, int out_size, void* d_ws, size_t ws_size,
                              hipStream_t stream) {
  (void)in_sizes; (void)n_in; (void)out_size; (void)ws_size;
  const float* q_fp  = (const float*)d_in[0];
  const float* v_ret = (const float*)d_in[1];
  const float* pi    = (const float*)d_in[2];
  const float* Wqs = (const float*)d_in[3];  const float* bqs = (const float*)d_in[4];
  const float* Wks = (const float*)d_in[5];  const float* bks = (const float*)d_in[6];
  const float* Wvs = (const float*)d_in[7];  const float* bvs = (const float*)d_in[8];
  const float* Wqe = (const float*)d_in[9];  const float* bqe = (const float*)d_in[10];
  const float* Wke = (const float*)d_in[11]; const float* bke = (const float*)d_in[12];
  const float* Wve = (const float*)d_in[13]; const float* bve = (const float*)d_in[14];
  const float* W1  = (const float*)d_in[15]; const float* b1  = (const float*)d_in[16];
  const float* W2  = (const float*)d_in[17]; const float* b2  = (const float*)d_in[18];
  const float* gamma = (const float*)d_in[19];
  const float* ew    = (const float*)d_in[20];

  char* w = (char*)d_ws;
  unsigned short* WqT = (unsigned short*)(w + 0);          // 512x512 bf16
  unsigned short* WkT = (unsigned short*)(w + 524288);     // 1024x512
  unsigned short* W1T = (unsigned short*)(w + 1572864);    // 256x1024
  unsigned short* W2T = (unsigned short*)(w + 2097152);    // 256x256
  float* bq   = (float*)(w + 2228224);                     // 512
  float* bk   = (float*)(w + 2230272);                     // 1024
  float* q2   = (float*)(w + 2234368);                     // 16384
  float* k2   = (float*)(w + 2299904);                     // 16384
  float* dsum = (float*)(w + 2365440);                     // 8
  unsigned short* ctx  = (unsigned short*)(w + 2365696);   // 16384x512 bf16 (16.8MB)
  unsigned short* hbuf = (unsigned short*)(w + 19142912);  // 16384x256 bf16 (8.4MB)
  unsigned short* Xq = (unsigned short*)(w + 35920128);    // 16384x512 (qs|qe)
  unsigned short* Xk = (unsigned short*)(w + 52697344);    // 16384x1024 (ks|vs|ke|ve)
  unsigned short* VT = (unsigned short*)(w + 86251776);    // 8x512x2048
  unsigned short* attn = (unsigned short*)(w + 103028992); // 16384x2048 bf16 unnorm
  unsigned short* fused = attn;                            // reuse (attn dead after PV)
  // sd chunk buffer (2 batches = exactly 32MiB) overlays ctx+hbuf, which are
  // dead until k_fused/MLP.
  unsigned* sdbuf = (unsigned*)(w + 2365696);
  float* rowsum = (float*)d_out;  // 64KB scratch in d_out; overwritten by final GEMM

  k_prep_w<<<4352, 256, 0, stream>>>(Wqs, Wqe, Wks, Wvs, Wke, Wve, W1, W2,
                                     bqs, bqe, bks, bvs, bke, bve,
                                     WqT, WkT, W1T, W2T, bq, bk, dsum);
  // projections straight from fp32 inputs: Xq=[q_struct|q_elec], Xk=[ks|vs|ke|ve]
  k_proj<<<dim3(128, 4), 512, 0, stream>>>(q_fp,  WqT, bq, Xq, 512, 512);
  k_proj<<<dim3(128, 8), 512, 0, stream>>>(v_ret, WkT, bk, Xk, 1024, 512);
  k_rowsq<<<4096, 256, 0, stream>>>(Xq, 512, 256, q2);
  k_rowsq<<<4096, 256, 0, stream>>>(Xk, 1024, 512, k2);
  // chunked (2 batches each): GEMMs once -> packed (s,d); then streaming softmax
  for (int c = 0; c < 4; ++c) {
    k_sd<<<dim3(16, 16, 2), 512, 0, stream>>>(Xq, Xk, q2, k2, 2 * c, dsum, sdbuf);
    k_softmax<<<1024, 256, 0, stream>>>(sdbuf, pi, dsum, gamma, ew, 2 * c,
                                        attn, rowsum);
  }
  // transpose v_struct/v_elec -> VT
  k_trans_vt<<<dim3(64, 16, 8), dim3(32, 8), 0, stream>>>(Xk, VT);
  // ctx = (attn @ [Vs|Ve]) / rowsum
  k_pv<<<dim3(64, 1, 8), 512, 0, stream>>>(attn, VT, rowsum, ctx);
  // fused features
  k_fused<<<16384, 256, 0, stream>>>(ctx, fused);
  // MLP: h = silu(fused @ W1 + b1); out = h @ W2 + b2 (fp32)
  k_gemm_bias<1><<<dim3(128, 2), 512, 0, stream>>>(fused, W1T, b1, hbuf, 256, 1024);
  k_gemm_bias<2><<<dim3(128, 2), 512, 0, stream>>>(hbuf, W2T, b2, d_out, 256, 256);
}